// Round 2
// baseline (129.448 us; speedup 1.0000x reference)
//
#include <hip/hip_runtime.h>
#include <math.h>

// PhyGate: elementwise physics gate over B rows of (b, v[3], w[3]).
// 4 rows per thread -> exact float4 vectorization of the (B,3) float32 layout.
// No local arrays / dynamic indexing anywhere -> everything stays in VGPRs.

struct Params {
    float dt, lw, lb, p1, p2, p3x, p3y, p3z, p5, r, coef;
};

__device__ __forceinline__ void phygate_row(
    float bj, float vx, float vy, float vz, float wx, float wy, float wz,
    const Params& P,
    float& ovx, float& ovy, float& ovz, float& owx, float& owy, float& owz)
{
    float g1 = 1.0f / (1.0f + expf(-(bj * P.lw + P.lb)));
    float g2 = 1.0f - g1;

    float dx = vx - wy * P.r;
    float dy = vy + wx * P.r;
    float al = P.coef * fabsf(vz) / sqrtf(dx * dx + dy * dy + 1e-6f);
    al = fminf(al, 0.4f);

    float oma = 1.0f - al;
    float vbx = oma * vx + al * P.r * wy;
    float vby = oma * vy - al * P.r * wx;
    float vbz = -P.p5 * vz;

    float c    = 1.5f * al / P.r;
    float om15 = 1.0f - 1.5f * al;
    float wbx  = -c * vy + om15 * wx;
    float wby  =  c * vx + om15 * wy;
    float wbz  = wz;

    float v2x = g1 * vx + g2 * vbx;
    float v2y = g1 * vy + g2 * vby;
    float v2z = g1 * vz + g2 * vbz;
    float w2x = g1 * wx + g2 * wbx;
    float w2y = g1 * wy + g2 * wby;
    float w2z = g1 * wz + g2 * wbz;

    float nv = sqrtf(v2x * v2x + v2y * v2y + v2z * v2z);
    float cx = w2y * v2z - w2z * v2y;
    float cy = w2z * v2x - w2x * v2z;
    float cz = w2x * v2y - w2y * v2x;

    float ax = -P.p1 * nv * v2x + P.p2 * cx + P.p3x;
    float ay = -P.p1 * nv * v2y + P.p2 * cy + P.p3y;
    float az = -P.p1 * nv * v2z + P.p2 * cz + P.p3z - 9.81f;

    ovx = v2x + ax * P.dt;
    ovy = v2y + ay * P.dt;
    ovz = v2z + az * P.dt;
    owx = w2x;
    owy = w2y;
    owz = w2z;
}

__device__ __forceinline__ Params load_params(
    const float* dt_p, const float* lin_w_p, const float* lin_b_p,
    const float* p1_p, const float* p2_p, const float* p3_p,
    const float* p4_p, const float* p5_p, const float* p6_p)
{
    Params P;
    P.dt = dt_p[0]; P.lw = lin_w_p[0]; P.lb = lin_b_p[0];
    P.p1 = p1_p[0]; P.p2 = p2_p[0];
    P.p3x = p3_p[0]; P.p3y = p3_p[1]; P.p3z = p3_p[2];
    P.p5 = p5_p[0]; P.r = p6_p[0];
    P.coef = p4_p[0] * (1.0f + P.p5);
    return P;
}

__global__ __launch_bounds__(256) void phygate_kernel(
    const float* __restrict__ b,
    const float* __restrict__ v,
    const float* __restrict__ w,
    const float* __restrict__ dt_p,
    const float* __restrict__ lin_w_p,
    const float* __restrict__ lin_b_p,
    const float* __restrict__ p1_p,
    const float* __restrict__ p2_p,
    const float* __restrict__ p3_p,
    const float* __restrict__ p4_p,
    const float* __restrict__ p5_p,
    const float* __restrict__ p6_p,
    float* __restrict__ out_v,   // B*3 floats
    float* __restrict__ out_w,   // B*3 floats
    int n_groups)                // number of full 4-row groups
{
    const int tid = blockIdx.x * blockDim.x + threadIdx.x;
    if (tid >= n_groups) return;

    const Params P = load_params(dt_p, lin_w_p, lin_b_p, p1_p, p2_p, p3_p,
                                 p4_p, p5_p, p6_p);

    const float4* b4 = (const float4*)b;
    const float4* v4 = (const float4*)v;
    const float4* w4 = (const float4*)w;

    const float4 bb = b4[tid];
    const float4 a0 = v4[3LL * tid + 0];
    const float4 a1 = v4[3LL * tid + 1];
    const float4 a2 = v4[3LL * tid + 2];
    const float4 c0 = w4[3LL * tid + 0];
    const float4 c1 = w4[3LL * tid + 1];
    const float4 c2 = w4[3LL * tid + 2];

    // rows: r0=(a0.x,a0.y,a0.z) r1=(a0.w,a1.x,a1.y) r2=(a1.z,a1.w,a2.x) r3=(a2.y,a2.z,a2.w)
    float o0x,o0y,o0z, q0x,q0y,q0z;
    float o1x,o1y,o1z, q1x,q1y,q1z;
    float o2x,o2y,o2z, q2x,q2y,q2z;
    float o3x,o3y,o3z, q3x,q3y,q3z;

    phygate_row(bb.x, a0.x, a0.y, a0.z, c0.x, c0.y, c0.z, P, o0x,o0y,o0z, q0x,q0y,q0z);
    phygate_row(bb.y, a0.w, a1.x, a1.y, c0.w, c1.x, c1.y, P, o1x,o1y,o1z, q1x,q1y,q1z);
    phygate_row(bb.z, a1.z, a1.w, a2.x, c1.z, c1.w, c2.x, P, o2x,o2y,o2z, q2x,q2y,q2z);
    phygate_row(bb.w, a2.y, a2.z, a2.w, c1.w == c1.w ? c2.y : c2.y, c2.z, c2.w, P, o3x,o3y,o3z, q3x,q3y,q3z);

    float4* ov4 = (float4*)out_v;
    float4* ow4 = (float4*)out_w;
    ov4[3LL * tid + 0] = make_float4(o0x, o0y, o0z, o1x);
    ov4[3LL * tid + 1] = make_float4(o1y, o1z, o2x, o2y);
    ov4[3LL * tid + 2] = make_float4(o2z, o3x, o3y, o3z);
    ow4[3LL * tid + 0] = make_float4(q0x, q0y, q0z, q1x);
    ow4[3LL * tid + 1] = make_float4(q1y, q1z, q2x, q2y);
    ow4[3LL * tid + 2] = make_float4(q2z, q3x, q3y, q3z);
}

// Scalar tail kernel for the (B % 4) leftover rows. For B=2,000,000 this is
// never launched, but keeps the code correct for any B.
__global__ __launch_bounds__(64) void phygate_tail_kernel(
    const float* __restrict__ b,
    const float* __restrict__ v,
    const float* __restrict__ w,
    const float* __restrict__ dt_p,
    const float* __restrict__ lin_w_p,
    const float* __restrict__ lin_b_p,
    const float* __restrict__ p1_p,
    const float* __restrict__ p2_p,
    const float* __restrict__ p3_p,
    const float* __restrict__ p4_p,
    const float* __restrict__ p5_p,
    const float* __restrict__ p6_p,
    float* __restrict__ out_v,
    float* __restrict__ out_w,
    int row_start, int B)
{
    const int row = row_start + blockIdx.x * blockDim.x + threadIdx.x;
    if (row >= B) return;

    const Params P = load_params(dt_p, lin_w_p, lin_b_p, p1_p, p2_p, p3_p,
                                 p4_p, p5_p, p6_p);

    float ox, oy, oz, qx, qy, qz;
    phygate_row(b[row],
                v[3 * row], v[3 * row + 1], v[3 * row + 2],
                w[3 * row], w[3 * row + 1], w[3 * row + 2],
                P, ox, oy, oz, qx, qy, qz);
    out_v[3 * row]     = ox;
    out_v[3 * row + 1] = oy;
    out_v[3 * row + 2] = oz;
    out_w[3 * row]     = qx;
    out_w[3 * row + 1] = qy;
    out_w[3 * row + 2] = qz;
}

extern "C" void kernel_launch(void* const* d_in, const int* in_sizes, int n_in,
                              void* d_out, int out_size, void* d_ws, size_t ws_size,
                              hipStream_t stream) {
    const float* b     = (const float*)d_in[0];
    const float* v     = (const float*)d_in[1];
    const float* w     = (const float*)d_in[2];
    const float* dt    = (const float*)d_in[3];
    const float* lin_w = (const float*)d_in[4];
    const float* lin_b = (const float*)d_in[5];
    const float* p1    = (const float*)d_in[6];
    const float* p2    = (const float*)d_in[7];
    const float* p3    = (const float*)d_in[8];
    const float* p4    = (const float*)d_in[9];
    const float* p5    = (const float*)d_in[10];
    const float* p6    = (const float*)d_in[11];

    const int B = in_sizes[0];           // b has B elements
    float* out_v = (float*)d_out;        // first output: v_new, B*3 floats
    float* out_w = out_v + (size_t)3 * B;

    const int n_groups = B / 4;
    const int tail     = B - n_groups * 4;

    if (n_groups > 0) {
        const int threads = 256;
        const int blocks = (n_groups + threads - 1) / threads;
        phygate_kernel<<<blocks, threads, 0, stream>>>(
            b, v, w, dt, lin_w, lin_b, p1, p2, p3, p4, p5, p6,
            out_v, out_w, n_groups);
    }
    if (tail > 0) {
        phygate_tail_kernel<<<1, 64, 0, stream>>>(
            b, v, w, dt, lin_w, lin_b, p1, p2, p3, p4, p5, p6,
            out_v, out_w, n_groups * 4, B);
    }
}